// Round 1
// 538.038 us; speedup vs baseline: 1.1269x; 1.1269x over previous
//
#include <hip/hip_runtime.h>

typedef unsigned short u16;
typedef unsigned int u32;

typedef __bf16 bf16x8 __attribute__((ext_vector_type(8)));
typedef float f32x4 __attribute__((ext_vector_type(4)));

#define EPI_BF16 0
#define EPI_ELU1 1
#define EPI_RELU 2
#define EPI_ADDRES_F32 3

__device__ __forceinline__ float bf2f(u16 x) {
    u32 u = ((u32)x) << 16;
    return __uint_as_float(u);
}
__device__ __forceinline__ u16 f2bf(float f) {
    u32 u = __float_as_uint(f);
    u32 r = (u + 0x7FFFu + ((u >> 16) & 1u)) >> 16;
    return (u16)r;
}

// async global->LDS, 16B per lane; LDS dest = wave-uniform base + lane*16
__device__ __forceinline__ void gload_lds16(const u16* g, u16* l) {
    __builtin_amdgcn_global_load_lds(
        (const __attribute__((address_space(1))) u32*)g,
        (__attribute__((address_space(3))) u32*)l, 16, 0, 0);
}

// ---------------------------------------------------------------------------
// fp32 -> bf16 conversion (vectorized, 4 elems/thread)
// ---------------------------------------------------------------------------
__global__ __launch_bounds__(256) void f2b_k(const float* __restrict__ in,
                                             u16* __restrict__ out, int n) {
    int i = (blockIdx.x * 256 + threadIdx.x) * 4;
    if (i >= n) return;
    float4 f = *(const float4*)(in + i);
    ushort4 o;
    o.x = f2bf(f.x); o.y = f2bf(f.y); o.z = f2bf(f.z); o.w = f2bf(f.w);
    *(ushort4*)(out + i) = o;
}

// ---------------------------------------------------------------------------
// Weight transpose + cast: in fp32 [R][C] -> out bf16 [C][R]
// ---------------------------------------------------------------------------
__global__ void transpose_k(const float* __restrict__ in, u16* __restrict__ out,
                            int R, int C) {
    int idx = blockIdx.x * 256 + threadIdx.x;
    if (idx >= R * C) return;
    int c = idx / R, r = idx % R;        // out index = c*R + r
    out[idx] = f2bf(in[(long)r * C + c]);
}

// ---------------------------------------------------------------------------
// GEMM: C[M,N] = A[M,K] (bf16) @ Bt[N,K]^T (bf16), fp32 accum, fused epilogue.
// 128x128 tile, BK=32, 4 waves (2x2 of 64x64), mfma_f32_16x16x32_bf16.
// ---------------------------------------------------------------------------
__global__ __launch_bounds__(256) void gemm_bt(
    const u16* __restrict__ A, const u16* __restrict__ Bt,
    void* __restrict__ C, const float* __restrict__ Res,
    int M, int N, int K, int epi)
{
    __shared__ __align__(16) u16 As[128 * 32];
    __shared__ __align__(16) u16 Bs[128 * 32];

    int t = threadIdx.x;
    int m0 = blockIdx.y * 128, n0 = blockIdx.x * 128;
    int wave = t >> 6, lane = t & 63;
    int wm = (wave >> 1) * 64, wn = (wave & 1) * 64;
    int lrow = lane & 15, lk8 = (lane >> 4) * 8;

    f32x4 acc[4][4] = {};

    // staging: chunk = 8 u16 (16B). lane l of wave w covers chunk w*64+l
    // (rows w*16+[0,16)) and chunk 256+w*64+l (rows 64+w*16+[0,16)).
    int srow = wave * 16 + (lane >> 2);
    int scol = (lane & 3) * 8;
    const u16* pA0 = A + (long)(m0 + srow) * K + scol;
    const u16* pB0 = Bt + (long)(n0 + srow) * K + scol;
    const long s64 = (long)64 * K;
    u16* lA0 = As + wave * 512;          // byte base = wave*1024
    u16* lA1 = As + 2048 + wave * 512;
    u16* lB0 = Bs + wave * 512;
    u16* lB1 = Bs + 2048 + wave * 512;

    for (int k0 = 0; k0 < K; k0 += 32) {
        __syncthreads();                 // previous iter's LDS reads done
        gload_lds16(pA0 + k0, lA0);
        gload_lds16(pA0 + s64 + k0, lA1);
        gload_lds16(pB0 + k0, lB0);
        gload_lds16(pB0 + s64 + k0, lB1);
        __builtin_amdgcn_s_waitcnt(0);   // explicit vmcnt(0): LDS-DMA landed
        __syncthreads();

        bf16x8 af[4], bfr[4];
#pragma unroll
        for (int mi = 0; mi < 4; mi++)
            af[mi] = *(const bf16x8*)(As + (wm + mi * 16 + lrow) * 32 + lk8);
#pragma unroll
        for (int ni = 0; ni < 4; ni++)
            bfr[ni] = *(const bf16x8*)(Bs + (wn + ni * 16 + lrow) * 32 + lk8);
#pragma unroll
        for (int mi = 0; mi < 4; mi++)
#pragma unroll
            for (int ni = 0; ni < 4; ni++)
                acc[mi][ni] = __builtin_amdgcn_mfma_f32_16x16x32_bf16(
                    af[mi], bfr[ni], acc[mi][ni], 0, 0, 0);
    }

    // Epilogue: D[row=(lane>>4)*4+r][col=lane&15] per 16x16 tile (verified m89/m91)
    int rq = (lane >> 4) * 4;
    int colb = n0 + wn + (lane & 15);
#pragma unroll
    for (int mi = 0; mi < 4; mi++) {
#pragma unroll
        for (int ni = 0; ni < 4; ni++) {
#pragma unroll
            for (int r = 0; r < 4; r++) {
                int row = m0 + wm + mi * 16 + rq + r;
                int col = colb + ni * 16;
                long idx = (long)row * N + col;
                float v0 = acc[mi][ni][r];
                if (epi == EPI_ELU1) {
                    float v = v0 > 0.f ? v0 + 1.f : __expf(v0);
                    ((u16*)C)[idx] = f2bf(v);
                } else if (epi == EPI_RELU) {
                    ((u16*)C)[idx] = f2bf(v0 > 0.f ? v0 : 0.f);
                } else if (epi == EPI_ADDRES_F32) {
                    ((float*)C)[idx] = v0 + Res[idx];
                } else {
                    ((u16*)C)[idx] = f2bf(v0);
                }
            }
        }
    }
}

// ---------------------------------------------------------------------------
// KV stage 1: per (bh, 64-s split) partial KVp[d][v] = sum_s K[s,d]*V[s,v]
// and KsPart[d] = sum_s K[s,d]. grid (32, 64), 256 threads.
// ---------------------------------------------------------------------------
__global__ __launch_bounds__(256) void kv_part(
    const u16* __restrict__ Kf, const u16* __restrict__ Vf,
    float* __restrict__ Part, float* __restrict__ KsPart)
{
    __shared__ float sKf[64 * 68];   // stride 68: conflict-light, 16B aligned
    __shared__ float sVf[64 * 68];
    int bh = blockIdx.x;
    int b = bh >> 3, h = bh & 7;
    int s0 = blockIdx.y * 64;
    int t = threadIdx.x;
    int d = t & 63, vg = t >> 6;

    {   // stage FULL 64x64 K and V tiles, bf16 -> fp32 (256 thr x 16 elems)
        int row = t >> 2, c16 = (t & 3) * 16;
        long g = ((long)b * 4096 + s0 + row) * 512 + h * 64 + c16;
        uint4 kk0 = *(const uint4*)(Kf + g);
        uint4 kk1 = *(const uint4*)(Kf + g + 8);
        uint4 vv0 = *(const uint4*)(Vf + g);
        uint4 vv1 = *(const uint4*)(Vf + g + 8);
        float* dk = sKf + row * 68 + c16;
        float* dv = sVf + row * 68 + c16;
        u32 kw[8] = {kk0.x, kk0.y, kk0.z, kk0.w, kk1.x, kk1.y, kk1.z, kk1.w};
        u32 vw[8] = {vv0.x, vv0.y, vv0.z, vv0.w, vv1.x, vv1.y, vv1.z, vv1.w};
#pragma unroll
        for (int j = 0; j < 8; j++) {
            dk[2 * j]     = __uint_as_float(kw[j] << 16);
            dk[2 * j + 1] = __uint_as_float(kw[j] & 0xFFFF0000u);
            dv[2 * j]     = __uint_as_float(vw[j] << 16);
            dv[2 * j + 1] = __uint_as_float(vw[j] & 0xFFFF0000u);
        }
    }
    __syncthreads();

    float acc[16] = {};
    float ks = 0.f;
#pragma unroll 4
    for (int s = 0; s < 64; s++) {
        float kd = sKf[s * 68 + d];
        if (vg == 0) ks += kd;                    // wave-uniform branch
        const float* vr = sVf + s * 68 + vg * 16; // wave-uniform -> broadcast
        float4 v0 = *(const float4*)(vr);
        float4 v1 = *(const float4*)(vr + 4);
        float4 v2 = *(const float4*)(vr + 8);
        float4 v3 = *(const float4*)(vr + 12);
        acc[0]  += kd * v0.x; acc[1]  += kd * v0.y;
        acc[2]  += kd * v0.z; acc[3]  += kd * v0.w;
        acc[4]  += kd * v1.x; acc[5]  += kd * v1.y;
        acc[6]  += kd * v1.z; acc[7]  += kd * v1.w;
        acc[8]  += kd * v2.x; acc[9]  += kd * v2.y;
        acc[10] += kd * v2.z; acc[11] += kd * v2.w;
        acc[12] += kd * v3.x; acc[13] += kd * v3.y;
        acc[14] += kd * v3.z; acc[15] += kd * v3.w;
    }
    float* pp = Part + ((long)bh * 64 + blockIdx.y) * 4096 + d * 64 + vg * 16;
#pragma unroll
    for (int j = 0; j < 16; j++) pp[j] = acc[j];
    if (vg == 0) KsPart[((bh * 64) + blockIdx.y) * 64 + d] = ks;
}

// ---------------------------------------------------------------------------
// KV stage 2: KV[bh][dv] = sum over 64 splits; Ksum folded into tail blocks.
// grid 520 x 256: idx<131072 -> KV, else -> Ksum (2048 entries).
// ---------------------------------------------------------------------------
__global__ __launch_bounds__(256) void kv_reduce(
    const float* __restrict__ Part, const float* __restrict__ KsPart,
    float* __restrict__ KV, float* __restrict__ Ksum)
{
    int i = blockIdx.x * 256 + threadIdx.x;
    if (i < 131072) {
        int bh = i >> 12, dv = i & 4095;
        const float* p = Part + (long)bh * 64 * 4096 + dv;
        float s = 0.f;
#pragma unroll 8
        for (int sp = 0; sp < 64; sp++) s += p[(long)sp * 4096];
        KV[i] = s;
    } else if (i < 133120) {
        int j = i - 131072;
        int bh = j >> 6, d = j & 63;
        const float* p = KsPart + bh * 64 * 64 + d;
        float s = 0.f;
#pragma unroll 8
        for (int sp = 0; sp < 64; sp++) s += p[sp * 64];
        Ksum[j] = s;
    }
}

// ---------------------------------------------------------------------------
// msg[b,l,h,v] = (sum_d Q[b,l,h,d]*KV[bh][d][v]) / (Q . Ksum + eps)
//
// Round-1 rewrite: old version was LDS-op bound (per thread: 64 ds_bpermute +
// 64 ds_read_b32 per output row; MfmaUtil 0, VALUBusy 26%, HBM 2.9% -> pure
// latency). New structure:
//   - lane = v. KV column for this lane (KV[.][v], 64 fp32) is hoisted into
//     64 VGPRs once per block, read from an LDS-transposed copy sKVt[v][d].
//   - Q rows live in LDS fp32; the inner loop reads them as WAVE-UNIFORM
//     ds_read_b128 broadcasts (16 per row instead of 64 bpermute + 64 b32).
//   - Z = 1/(Q.Ksum+eps) computed once per row into sZ (no per-row shuffle
//     tree). All math stays fp32 -> numerics unchanged vs previous version.
// ---------------------------------------------------------------------------
__global__ __launch_bounds__(256) void msg_k(
    const u16* __restrict__ Q, const float* __restrict__ KV,
    const float* __restrict__ Ksum, u16* __restrict__ Msg)
{
    __shared__ float sKVt[64 * 68];  // [v][d], pad 68 (stride%32==4 -> 2-way max)
    __shared__ float sQ[64 * 68];    // [l_local][d] fp32
    __shared__ float sKs[64];
    __shared__ float sZ[64];

    int bh = blockIdx.x;
    int b = bh >> 3, h = bh & 7;
    int l0 = blockIdx.y * 64;
    int t = threadIdx.x, wave = t >> 6, lane = t & 63;

    {   // stage KV[bh] (fp32 [d][v]) -> sKVt[v][d] (transposed). 16 elems/thr.
        const float* src = KV + (long)bh * 4096 + t * 16;
        int d = t >> 2;              // source row (d index)
        int v0 = (t & 3) * 16;       // source col base (v index)
        float4 a0 = *(const float4*)(src);
        float4 a1 = *(const float4*)(src + 4);
        float4 a2 = *(const float4*)(src + 8);
        float4 a3 = *(const float4*)(src + 12);
        float tmp[16] = {a0.x, a0.y, a0.z, a0.w, a1.x, a1.y, a1.z, a1.w,
                         a2.x, a2.y, a2.z, a2.w, a3.x, a3.y, a3.z, a3.w};
#pragma unroll
        for (int j = 0; j < 16; j++) sKVt[(v0 + j) * 68 + d] = tmp[j];
    }
    {   // stage Q tile rows l0..l0+63 (bf16 -> fp32). 16 elems/thr.
        int row = t >> 2, c = (t & 3) * 16;
        const u16* src = Q + ((long)b * 4096 + l0 + row) * 512 + h * 64 + c;
        uint4 q0 = *(const uint4*)(src);
        uint4 q1 = *(const uint4*)(src + 8);
        float* dq = sQ + row * 68 + c;
        u32 qw[8] = {q0.x, q0.y, q0.z, q0.w, q1.x, q1.y, q1.z, q1.w};
#pragma unroll
        for (int j = 0; j < 8; j++) {
            dq[2 * j]     = __uint_as_float(qw[j] << 16);
            dq[2 * j + 1] = __uint_as_float(qw[j] & 0xFFFF0000u);
        }
    }
    if (t < 64) sKs[t] = Ksum[bh * 64 + t];
    __syncthreads();

    // hoist this lane's KV column into registers (one-time, 16x ds_read_b128)
    float kv[64];
    {
        const float* kr = sKVt + lane * 68;
#pragma unroll
        for (int j = 0; j < 16; j++) {
            float4 x = *(const float4*)(kr + 4 * j);
            kv[4 * j]     = x.x; kv[4 * j + 1] = x.y;
            kv[4 * j + 2] = x.z; kv[4 * j + 3] = x.w;
        }
    }
    // per-row normalizer (wave 0 only; sKs reads are uniform -> broadcast)
    if (t < 64) {
        const float* qr = sQ + t * 68;
        float zp = 0.f;
#pragma unroll
        for (int d = 0; d < 64; d++) zp += qr[d] * sKs[d];
        sZ[t] = 1.f / (zp + 1e-6f);
    }
    __syncthreads();

    const long obase = ((long)b * 4096 + l0) * 512 + h * 64 + lane;
    int lbase = wave * 16;
#pragma unroll 4
    for (int i = 0; i < 16; i++) {
        int ll = lbase + i;
        const float* qr = sQ + ll * 68;
        float a0 = 0.f, a1 = 0.f, a2 = 0.f, a3 = 0.f;  // 4 indep chains
#pragma unroll
        for (int db = 0; db < 16; db++) {
            float4 q4 = *(const float4*)(qr + 4 * db);  // wave-uniform bcast
            a0 += q4.x * kv[4 * db];
            a1 += q4.y * kv[4 * db + 1];
            a2 += q4.z * kv[4 * db + 2];
            a3 += q4.w * kv[4 * db + 3];
        }
        float acc = (a0 + a1) + (a2 + a3);
        Msg[obase + (long)ll * 512] = f2bf(acc * sZ[ll]);
    }
}

// ---------------------------------------------------------------------------
// LayerNorm over 512 cols, fp32 input, fp32 gamma/beta.
// out_f32 != 0 -> write fp32 to OutF, else bf16 to OutB.
// ---------------------------------------------------------------------------
__global__ __launch_bounds__(256) void ln_k(
    const float* __restrict__ X, const float* __restrict__ g,
    const float* __restrict__ bta, u16* __restrict__ OutB,
    float* __restrict__ OutF, int out_f32)
{
    int row = blockIdx.x;
    const float* x = X + (long)row * 512;
    int t = threadIdx.x;
    float x0 = x[t], x1 = x[t + 256];
    float s = x0 + x1, sq = x0 * x0 + x1 * x1;
#pragma unroll
    for (int off = 32; off > 0; off >>= 1) {
        s += __shfl_xor(s, off, 64);
        sq += __shfl_xor(sq, off, 64);
    }
    __shared__ float rs[4], rq[4];
    int wave = t >> 6, lane = t & 63;
    if (lane == 0) { rs[wave] = s; rq[wave] = sq; }
    __syncthreads();
    s = rs[0] + rs[1] + rs[2] + rs[3];
    sq = rq[0] + rq[1] + rq[2] + rq[3];
    float mu = s * (1.f / 512.f);
    float var = sq * (1.f / 512.f) - mu * mu;
    float rstd = rsqrtf(var + 1e-5f);
    float y0 = (x0 - mu) * rstd * g[t] + bta[t];
    float y1 = (x1 - mu) * rstd * g[t + 256] + bta[t + 256];
    if (out_f32) {
        OutF[(long)row * 512 + t] = y0;
        OutF[(long)row * 512 + t + 256] = y1;
    } else {
        OutB[(long)row * 512 + t] = f2bf(y0);
        OutB[(long)row * 512 + t + 256] = f2bf(y1);
    }
}

// ---------------------------------------------------------------------------
extern "C" void kernel_launch(void* const* d_in, const int* in_sizes, int n_in,
                              void* d_out, int out_size, void* d_ws, size_t ws_size,
                              hipStream_t stream) {
    const float* q  = (const float*)d_in[0];
    const float* k  = (const float*)d_in[1];
    const float* v  = (const float*)d_in[2];
    const float* Wq = (const float*)d_in[3];
    const float* Wk = (const float*)d_in[4];
    const float* Wv = (const float*)d_in[5];
    const float* Wm = (const float*)d_in[6];
    const float* W1 = (const float*)d_in[7];
    const float* W2 = (const float*)d_in[8];
    const float* g1 = (const float*)d_in[9];
    const float* b1 = (const float*)d_in[10];
    const float* g2 = (const float*)d_in[11];
    const float* b2 = (const float*)d_in[12];

    char* ws = (char*)d_ws;
    // workspace layout (bytes); high-water ~124MB
    u16* WTq = (u16*)(ws + 0);            // 512KB each
    u16* WTk = (u16*)(ws + 524288);
    u16* WTv = (u16*)(ws + 1048576);
    u16* WTm = (u16*)(ws + 1572864);
    u16* W1T = (u16*)(ws + 2097152);      // [2048,512] 2MB
    u16* W2T = (u16*)(ws + 4194304);      // [512,2048] 2MB
    u16* qc  = (u16*)(ws + 6291456);      // bf16 casts of q/k/v, 16.8MB each
    u16* kc  = (u16*)(ws + 23068672);
    u16* vc  = (u16*)(ws + 39845888);
    u16* Qb  = (u16*)(ws + 56623104);     // elu+1 projections
    u16* Kb  = (u16*)(ws + 73400320);
    u16* Vb  = (u16*)(ws + 90177536);
    float* KVb = (float*)(ws + 106954752); // 512KB
    float* KSb = (float*)(ws + 107479040); // 8KB
    u16* Msg = (u16*)(ws + 107487232);    // 16.8MB -> high-water 124264448
    float* Part = (float*)(ws + 23068672); // 33.5MB partial KV (kc/vc dead)
    float* KsPart = (float*)(ws + 6291456);// 512KB (qc dead after projections)
    float* xpre = (float*)(ws + 23068672); // 33.5MB (Part dead after reduce)
    u16* x1  = qc;                         // reuses qc (KsPart dead by LN1)
    u16* Hid = (u16*)(ws + 56623104);     // 67MB, reuses Qb..Msg (dead at FFN)

    // fp32 -> bf16 casts of activations
    f2b_k<<<dim3(8192), 256, 0, stream>>>(q, qc, 8388608);
    f2b_k<<<dim3(8192), 256, 0, stream>>>(k, kc, 8388608);
    f2b_k<<<dim3(8192), 256, 0, stream>>>(v, vc, 8388608);

    // weight transposes + cast ([in,out] fp32 -> [out,in] bf16)
    transpose_k<<<dim3(1024), 256, 0, stream>>>(Wq, WTq, 512, 512);
    transpose_k<<<dim3(1024), 256, 0, stream>>>(Wk, WTk, 512, 512);
    transpose_k<<<dim3(1024), 256, 0, stream>>>(Wv, WTv, 512, 512);
    transpose_k<<<dim3(1024), 256, 0, stream>>>(Wm, WTm, 512, 512);
    transpose_k<<<dim3(4096), 256, 0, stream>>>(W1, W1T, 512, 2048);
    transpose_k<<<dim3(4096), 256, 0, stream>>>(W2, W2T, 2048, 512);

    // projections with fused activation
    gemm_bt<<<dim3(4, 128), 256, 0, stream>>>(qc, WTq, Qb, nullptr, 16384, 512, 512, EPI_ELU1);
    gemm_bt<<<dim3(4, 128), 256, 0, stream>>>(kc, WTk, Kb, nullptr, 16384, 512, 512, EPI_ELU1);
    gemm_bt<<<dim3(4, 128), 256, 0, stream>>>(vc, WTv, Vb, nullptr, 16384, 512, 512, EPI_BF16);

    // linear attention: two-stage KV (no atomics), then msg
    kv_part<<<dim3(32, 64), 256, 0, stream>>>(Kb, Vb, Part, KsPart);
    kv_reduce<<<dim3(520), 256, 0, stream>>>(Part, KsPart, KVb, KSb);
    msg_k<<<dim3(32, 64), 256, 0, stream>>>(Qb, KVb, KSb, Msg);

    // merge + residual(q fp32) + LN1 (bf16 out for FFN input)
    gemm_bt<<<dim3(4, 128), 256, 0, stream>>>(Msg, WTm, xpre, q, 16384, 512, 512, EPI_ADDRES_F32);
    ln_k<<<dim3(16384), 256, 0, stream>>>(xpre, g1, b1, x1, nullptr, 0);

    // FFN + residual(q fp32) + LN2 (fp32 out -> d_out)
    gemm_bt<<<dim3(16, 128), 256, 0, stream>>>(x1, W1T, Hid, nullptr, 16384, 2048, 512, EPI_RELU);
    gemm_bt<<<dim3(4, 128), 256, 0, stream>>>(Hid, W2T, xpre, q, 16384, 512, 2048, EPI_ADDRES_F32);
    ln_k<<<dim3(16384), 256, 0, stream>>>(xpre, g2, b2, nullptr, (float*)d_out, 1);
}

// Round 3
// 519.924 us; speedup vs baseline: 1.1661x; 1.0348x over previous
//
#include <hip/hip_runtime.h>

typedef unsigned short u16;
typedef unsigned int u32;

typedef __bf16 bf16x8 __attribute__((ext_vector_type(8)));
typedef float f32x4 __attribute__((ext_vector_type(4)));

#define EPI_BF16 0
#define EPI_ELU1 1
#define EPI_RELU 2
#define EPI_ADDRES_F32 3

__device__ __forceinline__ float bf2f(u16 x) {
    u32 u = ((u32)x) << 16;
    return __uint_as_float(u);
}
__device__ __forceinline__ u16 f2bf(float f) {
    u32 u = __float_as_uint(f);
    u32 r = (u + 0x7FFFu + ((u >> 16) & 1u)) >> 16;
    return (u16)r;
}

// async global->LDS, 16B per lane; LDS dest = wave-uniform base + lane*16
__device__ __forceinline__ void gload_lds16(const u16* g, u16* l) {
    __builtin_amdgcn_global_load_lds(
        (const __attribute__((address_space(1))) u32*)g,
        (__attribute__((address_space(3))) u32*)l, 16, 0, 0);
}

// ---------------------------------------------------------------------------
// fp32 -> bf16 conversion (vectorized, 4 elems/thread)
// ---------------------------------------------------------------------------
__global__ __launch_bounds__(256) void f2b_k(const float* __restrict__ in,
                                             u16* __restrict__ out, int n) {
    int i = (blockIdx.x * 256 + threadIdx.x) * 4;
    if (i >= n) return;
    float4 f = *(const float4*)(in + i);
    ushort4 o;
    o.x = f2bf(f.x); o.y = f2bf(f.y); o.z = f2bf(f.z); o.w = f2bf(f.w);
    *(ushort4*)(out + i) = o;
}

// ---------------------------------------------------------------------------
// Weight transpose + cast: in fp32 [R][C] -> out bf16 [C][R]
// ---------------------------------------------------------------------------
__global__ void transpose_k(const float* __restrict__ in, u16* __restrict__ out,
                            int R, int C) {
    int idx = blockIdx.x * 256 + threadIdx.x;
    if (idx >= R * C) return;
    int c = idx / R, r = idx % R;        // out index = c*R + r
    out[idx] = f2bf(in[(long)r * C + c]);
}

// ---------------------------------------------------------------------------
// GEMM: C[M,N] = A[M,K] (bf16) @ Bt[N,K]^T (bf16), fp32 accum, fused epilogue.
// 128x128 tile, BK=32, 4 waves (2x2 of 64x64), mfma_f32_16x16x32_bf16.
//
// (1) double-buffered LDS 2-phase schedule (catalog T3 minimum): issue next
// K-tile's global_load_lds BEFORE computing current tile; single
// vmcnt(0)+barrier per K-step. (2) XCD-chunked blockIdx swizzle (T1,
// bijective; all gemm grids are %8==0): consecutive m-row tiles land on the
// same XCD L2 so A-operand re-reads across n-blocks become L2 hits.
// ---------------------------------------------------------------------------
__global__ __launch_bounds__(256) void gemm_bt(
    const u16* __restrict__ A, const u16* __restrict__ Bt,
    void* __restrict__ C, const float* __restrict__ Res,
    int M, int N, int K, int epi)
{
    __shared__ __align__(16) u16 As[2][128 * 32];
    __shared__ __align__(16) u16 Bs[2][128 * 32];

    int t = threadIdx.x;

    // XCD-chunked swizzle: orig id i dispatches to XCD i%8; remap so each XCD
    // owns a contiguous chunk of (m-major) tile space.
    int gx = gridDim.x;
    int nwg = gx * gridDim.y;
    int bid = blockIdx.y * gx + blockIdx.x;
    if ((nwg & 7) == 0) {
        int cpx = nwg >> 3;
        bid = (bid & 7) * cpx + (bid >> 3);
    }
    int m0 = (bid / gx) * 128, n0 = (bid % gx) * 128;

    int wave = t >> 6, lane = t & 63;
    int wm = (wave >> 1) * 64, wn = (wave & 1) * 64;
    int lrow = lane & 15, lk8 = (lane >> 4) * 8;

    f32x4 acc[4][4] = {};

    // staging: chunk = 8 u16 (16B). lane l of wave w covers chunk w*64+l
    // (rows w*16+[0,16)) and chunk 256+w*64+l (rows 64+w*16+[0,16)).
    int srow = wave * 16 + (lane >> 2);
    int scol = (lane & 3) * 8;
    const u16* pA0 = A + (long)(m0 + srow) * K + scol;
    const u16* pB0 = Bt + (long)(n0 + srow) * K + scol;
    const long s64 = (long)64 * K;

    int nt = K >> 5;
    int cur = 0;

    // prologue: stage tile 0 into buffer 0
    {
        u16* a = As[0] + wave * 512;
        u16* b = Bs[0] + wave * 512;
        gload_lds16(pA0, a);
        gload_lds16(pA0 + s64, a + 2048);
        gload_lds16(pB0, b);
        gload_lds16(pB0 + s64, b + 2048);
    }
    __builtin_amdgcn_s_waitcnt(0);
    __syncthreads();

    for (int kt = 0; kt < nt; ++kt) {
        // issue next tile's loads into the other buffer (overlaps compute)
        if (kt + 1 < nt) {
            int k0 = (kt + 1) << 5;
            u16* a = As[cur ^ 1] + wave * 512;
            u16* b = Bs[cur ^ 1] + wave * 512;
            gload_lds16(pA0 + k0, a);
            gload_lds16(pA0 + s64 + k0, a + 2048);
            gload_lds16(pB0 + k0, b);
            gload_lds16(pB0 + s64 + k0, b + 2048);
        }

        const u16* As_c = As[cur];
        const u16* Bs_c = Bs[cur];
        bf16x8 af[4], bfr[4];
#pragma unroll
        for (int mi = 0; mi < 4; mi++)
            af[mi] = *(const bf16x8*)(As_c + (wm + mi * 16 + lrow) * 32 + lk8);
#pragma unroll
        for (int ni = 0; ni < 4; ni++)
            bfr[ni] = *(const bf16x8*)(Bs_c + (wn + ni * 16 + lrow) * 32 + lk8);
#pragma unroll
        for (int mi = 0; mi < 4; mi++)
#pragma unroll
            for (int ni = 0; ni < 4; ni++)
                acc[mi][ni] = __builtin_amdgcn_mfma_f32_16x16x32_bf16(
                    af[mi], bfr[ni], acc[mi][ni], 0, 0, 0);

        if (kt + 1 < nt) {
            __builtin_amdgcn_s_waitcnt(0);   // prefetch landed
            __syncthreads();                 // everyone done reading cur
            cur ^= 1;
        }
    }

    // Epilogue: D[row=(lane>>4)*4+r][col=lane&15] per 16x16 tile (verified m89/m91)
    int rq = (lane >> 4) * 4;
    int colb = n0 + wn + (lane & 15);
#pragma unroll
    for (int mi = 0; mi < 4; mi++) {
#pragma unroll
        for (int ni = 0; ni < 4; ni++) {
#pragma unroll
            for (int r = 0; r < 4; r++) {
                int row = m0 + wm + mi * 16 + rq + r;
                int col = colb + ni * 16;
                long idx = (long)row * N + col;
                float v0 = acc[mi][ni][r];
                if (epi == EPI_ELU1) {
                    float v = v0 > 0.f ? v0 + 1.f : __expf(v0);
                    ((u16*)C)[idx] = f2bf(v);
                } else if (epi == EPI_RELU) {
                    ((u16*)C)[idx] = f2bf(v0 > 0.f ? v0 : 0.f);
                } else if (epi == EPI_ADDRES_F32) {
                    ((float*)C)[idx] = v0 + Res[idx];
                } else {
                    ((u16*)C)[idx] = f2bf(v0);
                }
            }
        }
    }
}

// ---------------------------------------------------------------------------
// KV stage 1: per (bh, 64-s split) partial KVp[d][v] = sum_s K[s,d]*V[s,v]
// and KsPart[d] = sum_s K[s,d]. grid (32, 64), 256 threads.
// ---------------------------------------------------------------------------
__global__ __launch_bounds__(256) void kv_part(
    const u16* __restrict__ Kf, const u16* __restrict__ Vf,
    float* __restrict__ Part, float* __restrict__ KsPart)
{
    __shared__ float sKf[64 * 68];   // stride 68: conflict-light, 16B aligned
    __shared__ float sVf[64 * 68];
    int bh = blockIdx.x;
    int b = bh >> 3, h = bh & 7;
    int s0 = blockIdx.y * 64;
    int t = threadIdx.x;
    int d = t & 63, vg = t >> 6;

    {   // stage FULL 64x64 K and V tiles, bf16 -> fp32 (256 thr x 16 elems)
        int row = t >> 2, c16 = (t & 3) * 16;
        long g = ((long)b * 4096 + s0 + row) * 512 + h * 64 + c16;
        uint4 kk0 = *(const uint4*)(Kf + g);
        uint4 kk1 = *(const uint4*)(Kf + g + 8);
        uint4 vv0 = *(const uint4*)(Vf + g);
        uint4 vv1 = *(const uint4*)(Vf + g + 8);
        float* dk = sKf + row * 68 + c16;
        float* dv = sVf + row * 68 + c16;
        u32 kw[8] = {kk0.x, kk0.y, kk0.z, kk0.w, kk1.x, kk1.y, kk1.z, kk1.w};
        u32 vw[8] = {vv0.x, vv0.y, vv0.z, vv0.w, vv1.x, vv1.y, vv1.z, vv1.w};
#pragma unroll
        for (int j = 0; j < 8; j++) {
            dk[2 * j]     = __uint_as_float(kw[j] << 16);
            dk[2 * j + 1] = __uint_as_float(kw[j] & 0xFFFF0000u);
            dv[2 * j]     = __uint_as_float(vw[j] << 16);
            dv[2 * j + 1] = __uint_as_float(vw[j] & 0xFFFF0000u);
        }
    }
    __syncthreads();

    float acc[16] = {};
    float ks = 0.f;
#pragma unroll 4
    for (int s = 0; s < 64; s++) {
        float kd = sKf[s * 68 + d];
        if (vg == 0) ks += kd;                    // wave-uniform branch
        const float* vr = sVf + s * 68 + vg * 16; // wave-uniform -> broadcast
        float4 v0 = *(const float4*)(vr);
        float4 v1 = *(const float4*)(vr + 4);
        float4 v2 = *(const float4*)(vr + 8);
        float4 v3 = *(const float4*)(vr + 12);
        acc[0]  += kd * v0.x; acc[1]  += kd * v0.y;
        acc[2]  += kd * v0.z; acc[3]  += kd * v0.w;
        acc[4]  += kd * v1.x; acc[5]  += kd * v1.y;
        acc[6]  += kd * v1.z; acc[7]  += kd * v1.w;
        acc[8]  += kd * v2.x; acc[9]  += kd * v2.y;
        acc[10] += kd * v2.z; acc[11] += kd * v2.w;
        acc[12] += kd * v3.x; acc[13] += kd * v3.y;
        acc[14] += kd * v3.z; acc[15] += kd * v3.w;
    }
    float* pp = Part + ((long)bh * 64 + blockIdx.y) * 4096 + d * 64 + vg * 16;
#pragma unroll
    for (int j = 0; j < 16; j++) pp[j] = acc[j];
    if (vg == 0) KsPart[((bh * 64) + blockIdx.y) * 64 + d] = ks;
}

// ---------------------------------------------------------------------------
// KV stage 2: KV[bh][dv] = sum over 64 splits; Ksum folded into tail blocks.
// grid 520 x 256: idx<131072 -> KV, else -> Ksum (2048 entries).
// ---------------------------------------------------------------------------
__global__ __launch_bounds__(256) void kv_reduce(
    const float* __restrict__ Part, const float* __restrict__ KsPart,
    float* __restrict__ KV, float* __restrict__ Ksum)
{
    int i = blockIdx.x * 256 + threadIdx.x;
    if (i < 131072) {
        int bh = i >> 12, dv = i & 4095;
        const float* p = Part + (long)bh * 64 * 4096 + dv;
        float s = 0.f;
#pragma unroll 8
        for (int sp = 0; sp < 64; sp++) s += p[(long)sp * 4096];
        KV[i] = s;
    } else if (i < 133120) {
        int j = i - 131072;
        int bh = j >> 6, d = j & 63;
        const float* p = KsPart + bh * 64 * 64 + d;
        float s = 0.f;
#pragma unroll 8
        for (int sp = 0; sp < 64; sp++) s += p[sp * 64];
        Ksum[j] = s;
    }
}

// ---------------------------------------------------------------------------
// msg[b,l,h,v] = (sum_d Q[b,l,h,d]*KV[bh][d][v]) / (Q . Ksum + eps)
// lane = v; KV column in 64 VGPRs (from LDS-transposed copy); Q rows read as
// wave-uniform ds_read_b128 broadcasts; Z precomputed per row. All fp32.
// ---------------------------------------------------------------------------
__global__ __launch_bounds__(256) void msg_k(
    const u16* __restrict__ Q, const float* __restrict__ KV,
    const float* __restrict__ Ksum, u16* __restrict__ Msg)
{
    __shared__ float sKVt[64 * 68];  // [v][d], pad 68 (stride%32==4 -> 2-way max)
    __shared__ float sQ[64 * 68];    // [l_local][d] fp32
    __shared__ float sKs[64];
    __shared__ float sZ[64];

    int bh = blockIdx.x;
    int b = bh >> 3, h = bh & 7;
    int l0 = blockIdx.y * 64;
    int t = threadIdx.x, wave = t >> 6, lane = t & 63;

    {   // stage KV[bh] (fp32 [d][v]) -> sKVt[v][d] (transposed). 16 elems/thr.
        const float* src = KV + (long)bh * 4096 + t * 16;
        int d = t >> 2;              // source row (d index)
        int v0 = (t & 3) * 16;       // source col base (v index)
        float4 a0 = *(const float4*)(src);
        float4 a1 = *(const float4*)(src + 4);
        float4 a2 = *(const float4*)(src + 8);
        float4 a3 = *(const float4*)(src + 12);
        float tmp[16] = {a0.x, a0.y, a0.z, a0.w, a1.x, a1.y, a1.z, a1.w,
                         a2.x, a2.y, a2.z, a2.w, a3.x, a3.y, a3.z, a3.w};
#pragma unroll
        for (int j = 0; j < 16; j++) sKVt[(v0 + j) * 68 + d] = tmp[j];
    }
    {   // stage Q tile rows l0..l0+63 (bf16 -> fp32). 16 elems/thr.
        int row = t >> 2, c = (t & 3) * 16;
        const u16* src = Q + ((long)b * 4096 + l0 + row) * 512 + h * 64 + c;
        uint4 q0 = *(const uint4*)(src);
        uint4 q1 = *(const uint4*)(src + 8);
        float* dq = sQ + row * 68 + c;
        u32 qw[8] = {q0.x, q0.y, q0.z, q0.w, q1.x, q1.y, q1.z, q1.w};
#pragma unroll
        for (int j = 0; j < 8; j++) {
            dq[2 * j]     = __uint_as_float(qw[j] << 16);
            dq[2 * j + 1] = __uint_as_float(qw[j] & 0xFFFF0000u);
        }
    }
    if (t < 64) sKs[t] = Ksum[bh * 64 + t];
    __syncthreads();

    // hoist this lane's KV column into registers (one-time, 16x ds_read_b128)
    float kv[64];
    {
        const float* kr = sKVt + lane * 68;
#pragma unroll
        for (int j = 0; j < 16; j++) {
            float4 x = *(const float4*)(kr + 4 * j);
            kv[4 * j]     = x.x; kv[4 * j + 1] = x.y;
            kv[4 * j + 2] = x.z; kv[4 * j + 3] = x.w;
        }
    }
    // per-row normalizer (wave 0 only; sKs reads are uniform -> broadcast)
    if (t < 64) {
        const float* qr = sQ + t * 68;
        float zp = 0.f;
#pragma unroll
        for (int d = 0; d < 64; d++) zp += qr[d] * sKs[d];
        sZ[t] = 1.f / (zp + 1e-6f);
    }
    __syncthreads();

    const long obase = ((long)b * 4096 + l0) * 512 + h * 64 + lane;
    int lbase = wave * 16;
#pragma unroll 4
    for (int i = 0; i < 16; i++) {
        int ll = lbase + i;
        const float* qr = sQ + ll * 68;
        float a0 = 0.f, a1 = 0.f, a2 = 0.f, a3 = 0.f;  // 4 indep chains
#pragma unroll
        for (int db = 0; db < 16; db++) {
            float4 q4 = *(const float4*)(qr + 4 * db);  // wave-uniform bcast
            a0 += q4.x * kv[4 * db];
            a1 += q4.y * kv[4 * db + 1];
            a2 += q4.z * kv[4 * db + 2];
            a3 += q4.w * kv[4 * db + 3];
        }
        float acc = (a0 + a1) + (a2 + a3);
        Msg[obase + (long)ll * 512] = f2bf(acc * sZ[ll]);
    }
}

// ---------------------------------------------------------------------------
// LayerNorm over 512 cols, fp32 input, fp32 gamma/beta.
// out_f32 != 0 -> write fp32 to OutF, else bf16 to OutB.
// ---------------------------------------------------------------------------
__global__ __launch_bounds__(256) void ln_k(
    const float* __restrict__ X, const float* __restrict__ g,
    const float* __restrict__ bta, u16* __restrict__ OutB,
    float* __restrict__ OutF, int out_f32)
{
    int row = blockIdx.x;
    const float* x = X + (long)row * 512;
    int t = threadIdx.x;
    float x0 = x[t], x1 = x[t + 256];
    float s = x0 + x1, sq = x0 * x0 + x1 * x1;
#pragma unroll
    for (int off = 32; off > 0; off >>= 1) {
        s += __shfl_xor(s, off, 64);
        sq += __shfl_xor(sq, off, 64);
    }
    __shared__ float rs[4], rq[4];
    int wave = t >> 6, lane = t & 63;
    if (lane == 0) { rs[wave] = s; rq[wave] = sq; }
    __syncthreads();
    s = rs[0] + rs[1] + rs[2] + rs[3];
    sq = rq[0] + rq[1] + rq[2] + rq[3];
    float mu = s * (1.f / 512.f);
    float var = sq * (1.f / 512.f) - mu * mu;
    float rstd = rsqrtf(var + 1e-5f);
    float y0 = (x0 - mu) * rstd * g[t] + bta[t];
    float y1 = (x1 - mu) * rstd * g[t + 256] + bta[t + 256];
    if (out_f32) {
        OutF[(long)row * 512 + t] = y0;
        OutF[(long)row * 512 + t + 256] = y1;
    } else {
        OutB[(long)row * 512 + t] = f2bf(y0);
        OutB[(long)row * 512 + t + 256] = f2bf(y1);
    }
}

// ---------------------------------------------------------------------------
extern "C" void kernel_launch(void* const* d_in, const int* in_sizes, int n_in,
                              void* d_out, int out_size, void* d_ws, size_t ws_size,
                              hipStream_t stream) {
    const float* q  = (const float*)d_in[0];
    const float* k  = (const float*)d_in[1];
    const float* v  = (const float*)d_in[2];
    const float* Wq = (const float*)d_in[3];
    const float* Wk = (const float*)d_in[4];
    const float* Wv = (const float*)d_in[5];
    const float* Wm = (const float*)d_in[6];
    const float* W1 = (const float*)d_in[7];
    const float* W2 = (const float*)d_in[8];
    const float* g1 = (const float*)d_in[9];
    const float* b1 = (const float*)d_in[10];
    const float* g2 = (const float*)d_in[11];
    const float* b2 = (const float*)d_in[12];

    char* ws = (char*)d_ws;
    // workspace layout (bytes); high-water ~124MB
    u16* WTq = (u16*)(ws + 0);            // 512KB each
    u16* WTk = (u16*)(ws + 524288);
    u16* WTv = (u16*)(ws + 1048576);
    u16* WTm = (u16*)(ws + 1572864);
    u16* W1T = (u16*)(ws + 2097152);      // [2048,512] 2MB
    u16* W2T = (u16*)(ws + 4194304);      // [512,2048] 2MB
    u16* qc  = (u16*)(ws + 6291456);      // bf16 casts of q/k/v, 16.8MB each
    u16* kc  = (u16*)(ws + 23068672);
    u16* vc  = (u16*)(ws + 39845888);
    u16* Qb  = (u16*)(ws + 56623104);     // elu+1 projections
    u16* Kb  = (u16*)(ws + 73400320);
    u16* Vb  = (u16*)(ws + 90177536);
    float* KVb = (float*)(ws + 106954752); // 512KB
    float* KSb = (float*)(ws + 107479040); // 8KB
    u16* Msg = (u16*)(ws + 107487232);    // 16.8MB -> high-water 124264448
    float* Part = (float*)(ws + 23068672); // 33.5MB partial KV (kc/vc dead)
    float* KsPart = (float*)(ws + 6291456);// 512KB (qc dead after projections)
    float* xpre = (float*)(ws + 23068672); // 33.5MB (Part dead after reduce)
    u16* x1  = qc;                         // reuses qc (KsPart dead by LN1)
    u16* Hid = (u16*)(ws + 56623104);     // 67MB, reuses Qb..Msg (dead at FFN)

    // fp32 -> bf16 casts of activations
    f2b_k<<<dim3(8192), 256, 0, stream>>>(q, qc, 8388608);
    f2b_k<<<dim3(8192), 256, 0, stream>>>(k, kc, 8388608);
    f2b_k<<<dim3(8192), 256, 0, stream>>>(v, vc, 8388608);

    // weight transposes + cast ([in,out] fp32 -> [out,in] bf16)
    transpose_k<<<dim3(1024), 256, 0, stream>>>(Wq, WTq, 512, 512);
    transpose_k<<<dim3(1024), 256, 0, stream>>>(Wk, WTk, 512, 512);
    transpose_k<<<dim3(1024), 256, 0, stream>>>(Wv, WTv, 512, 512);
    transpose_k<<<dim3(1024), 256, 0, stream>>>(Wm, WTm, 512, 512);
    transpose_k<<<dim3(4096), 256, 0, stream>>>(W1, W1T, 512, 2048);
    transpose_k<<<dim3(4096), 256, 0, stream>>>(W2, W2T, 2048, 512);

    // projections with fused activation
    gemm_bt<<<dim3(4, 128), 256, 0, stream>>>(qc, WTq, Qb, nullptr, 16384, 512, 512, EPI_ELU1);
    gemm_bt<<<dim3(4, 128), 256, 0, stream>>>(kc, WTk, Kb, nullptr, 16384, 512, 512, EPI_ELU1);
    gemm_bt<<<dim3(4, 128), 256, 0, stream>>>(vc, WTv, Vb, nullptr, 16384, 512, 512, EPI_BF16);

    // linear attention: two-stage KV (no atomics), then msg
    kv_part<<<dim3(32, 64), 256, 0, stream>>>(Kb, Vb, Part, KsPart);
    kv_reduce<<<dim3(520), 256, 0, stream>>>(Part, KsPart, KVb, KSb);
    msg_k<<<dim3(32, 64), 256, 0, stream>>>(Qb, KVb, KSb, Msg);

    // merge + residual(q fp32) + LN1 (bf16 out for FFN input)
    gemm_bt<<<dim3(4, 128), 256, 0, stream>>>(Msg, WTm, xpre, q, 16384, 512, 512, EPI_ADDRES_F32);
    ln_k<<<dim3(16384), 256, 0, stream>>>(xpre, g1, b1, x1, nullptr, 0);

    // FFN + residual(q fp32) + LN2 (fp32 out -> d_out)
    gemm_bt<<<dim3(16, 128), 256, 0, stream>>>(x1, W1T, Hid, nullptr, 16384, 2048, 512, EPI_RELU);
    gemm_bt<<<dim3(4, 128), 256, 0, stream>>>(Hid, W2T, xpre, q, 16384, 512, 2048, EPI_ADDRES_F32);
    ln_k<<<dim3(16384), 256, 0, stream>>>(xpre, g2, b2, nullptr, (float*)d_out, 1);
}